// Round 1
// baseline (13900.322 us; speedup 1.0000x reference)
//
#include <hip/hip_runtime.h>

#define B_ 256
#define S_ 256
#define D_ 64
#define H_ 1024
#define G4 4096
#define TOUT 32

typedef unsigned short u16;
typedef __attribute__((ext_vector_type(8))) short short8;
typedef __attribute__((ext_vector_type(4))) float float4v;

__device__ __forceinline__ float bf2f(u16 b) {
  return __uint_as_float(((unsigned int)b) << 16);
}
__device__ __forceinline__ u16 f2bf(float f) {
  unsigned int u = __float_as_uint(f);
  unsigned int r = (u + 0x7fffu + ((u >> 16) & 1u)) >> 16;
  return (u16)r;
}
__device__ __forceinline__ unsigned pack2(float a, float b) {
  return (unsigned)f2bf(a) | ((unsigned)f2bf(b) << 16);
}
__device__ __forceinline__ float sigm(float x) {
  return 1.f / (1.f + __expf(-x));
}
__device__ __forceinline__ float tanh_(float x) {
  float xc = fminf(fmaxf(x, -15.f), 15.f);
  float e = __expf(2.f * xc);
  return (e - 1.f) / (e + 1.f);
}

// async global->LDS DMA, 16B per lane, dest = wave-uniform base + lane*16
__device__ __forceinline__ void gload_lds16(const void* g, void* l) {
  __builtin_amdgcn_global_load_lds(
      (const __attribute__((address_space(1))) void*)g,
      (__attribute__((address_space(3))) void*)l, 16, 0, 0);
}

__global__ __launch_bounds__(256) void cvt_kernel(const float* __restrict__ src,
                                                  u16* __restrict__ dst, int n) {
  for (int i = blockIdx.x * blockDim.x + threadIdx.x; i < n;
       i += gridDim.x * blockDim.x)
    dst[i] = f2bf(src[i]);
}

__global__ __launch_bounds__(256) void zero_kernel(uint4* __restrict__ p, int n16) {
  for (int i = blockIdx.x * blockDim.x + threadIdx.x; i < n16;
       i += gridDim.x * blockDim.x)
    p[i] = make_uint4(0u, 0u, 0u, 0u);
}

struct LayerDesc {
  const u16* A0; int lda0;
  const u16* A1; int lda1; int klen0;
  const void* W0; int ldw0;
  const void* W1; int ldw1; int Ktot;
  const float* bias;   // fp32 [4096] original gate-blocked
  const float* wcol;   // fp32 [4096] dec input column, or null
  const float* inp;    // fp32 [B] scalar input, or null
  float* c;
  u16* h;
  int active;
};

// Paired LSTM step: blockIdx.y<4 -> dA (layer0 @ t), >=4 -> dB (layer1 @ t-1).
// Each 64x64 tile: gates = [A0|A1] @ [W0|W1]^T + bias (+inp*wcol), fused cell.
//
// v2 (anti-bank-conflict restructure):
//  - A fragments loaded DIRECTLY from global in MFMA frag layout (no As LDS);
//    A is L2-resident (h buffers 0.5MB, X slice 32KB/tick), prefetched 1 chunk.
//  - B tile staged fragment-major: BsF[buf][unit=ni*2+ks][lane][8 bf16].
//    Reads are base+lane*16 -> ZERO bank conflicts (old layout was 8-way).
//    bf16 path stages via global_load_lds (dest = uniform base + lane*16).
//  - Double-buffered B, ONE __syncthreads per 64-wide K chunk.
template <bool WF32>
__global__ __launch_bounds__(256) void lstm_step_kernel(LayerDesc dA, LayerDesc dB)
{
  const bool second = (blockIdx.y >= 4);
  const LayerDesc d = second ? dB : dA;
  if (!d.active) return;

  __shared__ __align__(16) u16 BsF[2][8][64][8];  // 16 KB, frag-major, dbuf
  __shared__ float Gs[64][68];

  const int tid = threadIdx.x;
  const int m0 = (second ? (blockIdx.y - 4) : blockIdx.y) * 64;
  const int n0 = blockIdx.x * 64;
  const int ub = n0 >> 2;        // first hidden unit of this block
  const int lane = tid & 63;
  const int wv = tid >> 6;
  const int wm = (wv >> 1) * 32;
  const int wn = (wv & 1) * 32;
  const int l16 = lane & 15;
  const int quad = lane >> 4;    // 0..3
  const int klen0 = d.klen0;

  // ---- B staging geometry: slot0 = unit wv, slot1 = unit wv+4, elem = lane.
  // unit u covers local gate-cols (u>>1)*16 + l16, k-sub (u&1)*32 + quad*8.
  const int c0 = (wv >> 1) * 16 + l16;              // slot1 col = c0 + 32
  const int kloc = (wv & 1) * 32 + quad * 8;
  const int orow = (c0 & 3) * H_ + ub + (c0 >> 2);  // gate-col -> original W row; slot1 = +8
  const u16* w0h0 = (const u16*)d.W0 + (size_t)orow * d.ldw0;
  const u16* w0h1 = w0h0 + (size_t)8 * d.ldw0;
  const u16* w1h0 = (const u16*)d.W1 + (size_t)orow * d.ldw1;
  const u16* w1h1 = w1h0 + (size_t)8 * d.ldw1;
  const float* f0h0 = (const float*)d.W0 + (size_t)orow * d.ldw0;
  const float* f0h1 = f0h0 + (size_t)8 * d.ldw0;
  const float* f1h0 = (const float*)d.W1 + (size_t)orow * d.ldw1;
  const float* f1h1 = f1h0 + (size_t)8 * d.ldw1;

  // ---- A fragment pointers (direct global, MFMA layout: row l&15, k quad*8)
  const int ar0 = m0 + wm + l16;
  const u16* a00 = d.A0 + (size_t)ar0 * d.lda0;         // mi=0, first operand
  const u16* a01 = d.A0 + (size_t)(ar0 + 16) * d.lda0;  // mi=1
  const u16* a10 = d.A1 + (size_t)ar0 * d.lda1;
  const u16* a11 = d.A1 + (size_t)(ar0 + 16) * d.lda1;
  const int akoff = quad * 8;

  float4 fB[4];

  auto loadBf = [&](int kc) {  // fp32 fallback: 8 floats per slot into regs
    const int k = kc * 64 + kloc;
    const bool first = k < klen0;
    const int kk = first ? k : k - klen0;
    const float* p0 = (first ? f0h0 : f1h0) + kk;
    const float* p1 = (first ? f0h1 : f1h1) + kk;
    fB[0] = *(const float4*)p0;
    fB[1] = *(const float4*)(p0 + 4);
    fB[2] = *(const float4*)p1;
    fB[3] = *(const float4*)(p1 + 4);
  };

  auto issue_dma = [&](int kc, int buf) {  // bf16: async stage chunk kc
    const int k = kc * 64 + kloc;
    const bool first = k < klen0;
    const int kk = first ? k : k - klen0;
    gload_lds16((first ? w0h0 : w1h0) + kk, &BsF[buf][wv][0][0]);
    gload_lds16((first ? w0h1 : w1h1) + kk, &BsF[buf][wv + 4][0][0]);
  };

  auto loadA = [&](int kc, short8* ar) {
#pragma unroll
    for (int ks = 0; ks < 2; ++ks) {
      const int k = kc * 64 + ks * 32 + akoff;
      const bool first = k < klen0;
      const int kk = first ? k : k - klen0;
      ar[ks]     = *(const short8*)((first ? a00 : a10) + kk);
      ar[2 + ks] = *(const short8*)((first ? a01 : a11) + kk);
    }
  };

  float4v acc00 = {}, acc01 = {}, acc10 = {}, acc11 = {};
  short8 aA[4], aN[4];
  const int nch = d.Ktot >> 6;

  loadA(0, aA);
  if constexpr (WF32) loadBf(0);
  else issue_dma(0, 0);

  for (int kc = 0; kc < nch; ++kc) {
    const int buf = kc & 1;
    if constexpr (WF32) {  // pack + reg-staged LDS write (rare fallback path)
      uint4 bW0 = make_uint4(pack2(fB[0].x, fB[0].y), pack2(fB[0].z, fB[0].w),
                             pack2(fB[1].x, fB[1].y), pack2(fB[1].z, fB[1].w));
      uint4 bW1 = make_uint4(pack2(fB[2].x, fB[2].y), pack2(fB[2].z, fB[2].w),
                             pack2(fB[3].x, fB[3].y), pack2(fB[3].z, fB[3].w));
      *(uint4*)&BsF[buf][wv][lane][0]     = bW0;
      *(uint4*)&BsF[buf][wv + 4][lane][0] = bW1;
    }
    __syncthreads();  // drains DMA/A-loads of this chunk; hands buffers over
    const bool more = (kc + 1 < nch);
    if (more) {
      if constexpr (WF32) loadBf(kc + 1);
      else issue_dma(kc + 1, buf ^ 1);
      loadA(kc + 1, aN);  // in flight across MFMA + next barrier
    }
#pragma unroll
    for (int ks = 0; ks < 2; ++ks) {
      // frag-major: addr = base + lane*16 -> conflict-free ds_read_b128
      const short8 b0 = *(const short8*)&BsF[buf][(wn >> 3) + ks][lane][0];
      const short8 b1 = *(const short8*)&BsF[buf][(wn >> 3) + 2 + ks][lane][0];
      acc00 = __builtin_amdgcn_mfma_f32_16x16x32_bf16(aA[ks], b0, acc00, 0, 0, 0);
      acc01 = __builtin_amdgcn_mfma_f32_16x16x32_bf16(aA[ks], b1, acc01, 0, 0, 0);
      acc10 = __builtin_amdgcn_mfma_f32_16x16x32_bf16(aA[2 + ks], b0, acc10, 0, 0, 0);
      acc11 = __builtin_amdgcn_mfma_f32_16x16x32_bf16(aA[2 + ks], b1, acc11, 0, 0, 0);
    }
    if (more) {
#pragma unroll
      for (int i = 0; i < 4; ++i) aA[i] = aN[i];
    }
  }

  // spill gates to LDS (C/D layout: col = lane&15, row = quad*4 + reg)
#pragma unroll
  for (int rr = 0; rr < 4; ++rr) {
    Gs[wm + quad * 4 + rr][wn + l16]           = acc00[rr];
    Gs[wm + quad * 4 + rr][wn + 16 + l16]      = acc01[rr];
    Gs[wm + 16 + quad * 4 + rr][wn + l16]      = acc10[rr];
    Gs[wm + 16 + quad * 4 + rr][wn + 16 + l16] = acc11[rr];
  }
  __syncthreads();

  // fused LSTM cell: 64 batches x 16 units; local col 4u+g = gate g of unit ub+u
#pragma unroll
  for (int it = 0; it < 4; ++it) {
    const int p = tid + it * 256;
    const int bl = p >> 4;
    const int u = p & 15;
    const int J = ub + u;
    const int bg = m0 + bl;
    const float4v g = *(const float4v*)&Gs[bl][u * 4];
    float pi = g[0] + d.bias[J];
    float pf = g[1] + d.bias[H_ + J];
    float pg = g[2] + d.bias[2 * H_ + J];
    float po = g[3] + d.bias[3 * H_ + J];
    if (d.inp != nullptr) {
      const float iv = d.inp[bg];
      pi += iv * d.wcol[J];
      pf += iv * d.wcol[H_ + J];
      pg += iv * d.wcol[2 * H_ + J];
      po += iv * d.wcol[3 * H_ + J];
    }
    const size_t idx = (size_t)bg * H_ + J;
    const float c = d.c[idx];
    const float cn = sigm(pf) * c + sigm(pi) * tanh_(pg);
    d.c[idx] = cn;
    d.h[idx] = f2bf(sigm(po) * tanh_(cn));
  }
}

// pred[b] = fc_W . h1[b] + fc_b ; fp32 out + fp32 feedback
__global__ __launch_bounds__(256) void fc_kernel(
    const u16* __restrict__ h1, const float* __restrict__ fcW,
    const float* __restrict__ fcb, float* __restrict__ out,
    float* __restrict__ inp, int t)
{
  const int b = blockIdx.x;
  const int tid = threadIdx.x;
  const u16* hr = h1 + (size_t)b * H_ + tid * 4;
  const float* wr = fcW + tid * 4;
  float s = 0.f;
#pragma unroll
  for (int j = 0; j < 4; ++j) s += bf2f(hr[j]) * wr[j];
#pragma unroll
  for (int off = 32; off > 0; off >>= 1) s += __shfl_down(s, off, 64);
  __shared__ float red[4];
  if ((tid & 63) == 0) red[tid >> 6] = s;
  __syncthreads();
  if (tid == 0) {
    const float p = red[0] + red[1] + red[2] + red[3] + fcb[0];
    out[(size_t)b * TOUT + t] = p;
    inp[b] = p;
  }
}

extern "C" void kernel_launch(void* const* d_in, const int* in_sizes, int n_in,
                              void* d_out, int out_size, void* d_ws, size_t ws_size,
                              hipStream_t stream)
{
  const float* X     = (const float*)d_in[0];
  const float* eWih0 = (const float*)d_in[1];
  const float* eWhh0 = (const float*)d_in[2];
  const float* eb0   = (const float*)d_in[3];
  const float* eWih1 = (const float*)d_in[4];
  const float* eWhh1 = (const float*)d_in[5];
  const float* eb1   = (const float*)d_in[6];
  const float* dWih0 = (const float*)d_in[7];
  const float* dWhh0 = (const float*)d_in[8];
  const float* db0   = (const float*)d_in[9];
  const float* dWih1 = (const float*)d_in[10];
  const float* dWhh1 = (const float*)d_in[11];
  const float* db1   = (const float*)d_in[12];
  const float* fcW   = (const float*)d_in[13];
  const float* fcb   = (const float*)d_in[14];
  float* out = (float*)d_out;

  char* ws = (char*)d_ws;
  size_t off = 0;
  auto alloc = [&](size_t bytes) -> void* {
    void* p = ws + off;
    off += (bytes + 255) & ~(size_t)255;
    return p;
  };
  // state block first (zeroed every call)
  u16* h0buf[2], *h1buf[2];
  h0buf[0] = (u16*)alloc((size_t)B_ * H_ * 2);
  h0buf[1] = (u16*)alloc((size_t)B_ * H_ * 2);
  h1buf[0] = (u16*)alloc((size_t)B_ * H_ * 2);
  h1buf[1] = (u16*)alloc((size_t)B_ * H_ * 2);
  float* C0  = (float*)alloc((size_t)B_ * H_ * 4);
  float* C1  = (float*)alloc((size_t)B_ * H_ * 4);
  float* INP = (float*)alloc(B_ * 4);
  const size_t zbytes = off;
  u16* XB = (u16*)alloc((size_t)B_ * S_ * D_ * 2);
  // bf16 weight copies (fast path), original flat layouts
  u16* WB_eWih0 = (u16*)alloc((size_t)G4 * D_ * 2);
  u16* WB_eWhh0 = (u16*)alloc((size_t)G4 * H_ * 2);
  u16* WB_eWih1 = (u16*)alloc((size_t)G4 * H_ * 2);
  u16* WB_eWhh1 = (u16*)alloc((size_t)G4 * H_ * 2);
  u16* WB_dWhh0 = (u16*)alloc((size_t)G4 * H_ * 2);
  u16* WB_dWih1 = (u16*)alloc((size_t)G4 * H_ * 2);
  u16* WB_dWhh1 = (u16*)alloc((size_t)G4 * H_ * 2);
  const size_t need_full = off;
  const bool fast = (ws_size >= need_full);

  zero_kernel<<<dim3(256), dim3(256), 0, stream>>>((uint4*)ws, (int)(zbytes / 16));
  cvt_kernel<<<dim3(1024), dim3(256), 0, stream>>>(X, XB, B_ * S_ * D_);
  if (fast) {
    cvt_kernel<<<dim3(256), dim3(256), 0, stream>>>(eWih0, WB_eWih0, G4 * D_);
    cvt_kernel<<<dim3(1024), dim3(256), 0, stream>>>(eWhh0, WB_eWhh0, G4 * H_);
    cvt_kernel<<<dim3(1024), dim3(256), 0, stream>>>(eWih1, WB_eWih1, G4 * H_);
    cvt_kernel<<<dim3(1024), dim3(256), 0, stream>>>(eWhh1, WB_eWhh1, G4 * H_);
    cvt_kernel<<<dim3(1024), dim3(256), 0, stream>>>(dWhh0, WB_dWhh0, G4 * H_);
    cvt_kernel<<<dim3(1024), dim3(256), 0, stream>>>(dWih1, WB_dWih1, G4 * H_);
    cvt_kernel<<<dim3(1024), dim3(256), 0, stream>>>(dWhh1, WB_dWhh1, G4 * H_);
  }

  auto mk = [&](const u16* A0, int lda0, const u16* A1, int lda1, int klen0,
                const void* W0b, const void* W0f, int ldw0,
                const void* W1b, const void* W1f, int ldw1, int Ktot,
                const float* bias, const float* wcol, const float* inp,
                float* c, u16* h) {
    LayerDesc d;
    d.A0 = A0; d.lda0 = lda0; d.A1 = A1; d.lda1 = lda1; d.klen0 = klen0;
    d.W0 = fast ? W0b : W0f; d.ldw0 = ldw0;
    d.W1 = fast ? W1b : W1f; d.ldw1 = ldw1; d.Ktot = Ktot;
    d.bias = bias; d.wcol = wcol; d.inp = inp; d.c = c; d.h = h;
    d.active = 1;
    return d;
  };
  LayerDesc off_d = {};
  off_d.active = 0;

  auto launch = [&](dim3 grid, const LayerDesc& a, const LayerDesc& b) {
    if (fast)
      lstm_step_kernel<false><<<grid, dim3(256), 0, stream>>>(a, b);
    else
      lstm_step_kernel<true><<<grid, dim3(256), 0, stream>>>(a, b);
  };

  // encoder, layer-pipelined: tick u runs L0(t=u) and L1(t=u-1) concurrently.
  // h ping-pong: L(t) reads hbuf[t&1], writes hbuf[(t+1)&1].
  for (int u = 0; u <= S_; ++u) {
    LayerDesc d0 = off_d, d1 = off_d;
    if (u < S_) {
      const int t = u;
      d0 = mk(XB + t * D_, S_ * D_, h0buf[t & 1], H_, D_,
              WB_eWih0, eWih0, D_, WB_eWhh0, eWhh0, H_, 1088,
              eb0, nullptr, nullptr, C0, h0buf[(t + 1) & 1]);
    }
    if (u >= 1) {
      const int t = u - 1;
      d1 = mk(h0buf[(t + 1) & 1], H_, h1buf[t & 1], H_, H_,
              WB_eWih1, eWih1, H_, WB_eWhh1, eWhh1, H_, 2048,
              eb1, nullptr, nullptr, C1, h1buf[(t + 1) & 1]);
    }
    launch(dim3(64, 8), d0, d1);
  }

  // decoder: strictly sequential (pred feedback), single-layer launches
  for (int t = 0; t < TOUT; ++t) {
    u16* h0i = h0buf[t & 1]; u16* h0o = h0buf[(t + 1) & 1];
    u16* h1i = h1buf[t & 1]; u16* h1o = h1buf[(t + 1) & 1];
    LayerDesc dl0 = mk(h0i, H_, h0i, H_, 1024,
                       WB_dWhh0, dWhh0, H_, WB_dWhh0, dWhh0, H_, 1024,
                       db0, dWih0, INP, C0, h0o);
    launch(dim3(64, 4), dl0, off_d);
    LayerDesc dl1 = mk(h0o, H_, h1i, H_, H_,
                       WB_dWih1, dWih1, H_, WB_dWhh1, dWhh1, H_, 2048,
                       db1, nullptr, nullptr, C1, h1o);
    launch(dim3(64, 4), dl1, off_d);
    fc_kernel<<<dim3(B_), dim3(256), 0, stream>>>(h1o, fcW, fcb, out, INP, t);
  }
}

// Round 2
// 10453.157 us; speedup vs baseline: 1.3298x; 1.3298x over previous
//
#include <hip/hip_runtime.h>

#define B_ 256
#define S_ 256
#define D_ 64
#define H_ 1024
#define G4 4096
#define TOUT 32

typedef unsigned short u16;
typedef __attribute__((ext_vector_type(8))) short short8;
typedef __attribute__((ext_vector_type(4))) float float4v;

__device__ __forceinline__ float bf2f(u16 b) {
  return __uint_as_float(((unsigned int)b) << 16);
}
__device__ __forceinline__ u16 f2bf(float f) {
  unsigned int u = __float_as_uint(f);
  unsigned int r = (u + 0x7fffu + ((u >> 16) & 1u)) >> 16;
  return (u16)r;
}
__device__ __forceinline__ unsigned pack2(float a, float b) {
  return (unsigned)f2bf(a) | ((unsigned)f2bf(b) << 16);
}
__device__ __forceinline__ float sigm(float x) {
  return 1.f / (1.f + __expf(-x));
}
__device__ __forceinline__ float tanh_(float x) {
  float xc = fminf(fmaxf(x, -15.f), 15.f);
  float e = __expf(2.f * xc);
  return (e - 1.f) / (e + 1.f);
}

__global__ __launch_bounds__(256) void cvt_kernel(const float* __restrict__ src,
                                                  u16* __restrict__ dst, int n) {
  for (int i = blockIdx.x * blockDim.x + threadIdx.x; i < n;
       i += gridDim.x * blockDim.x)
    dst[i] = f2bf(src[i]);
}

__global__ __launch_bounds__(256) void zero_kernel(uint4* __restrict__ p, int n16) {
  for (int i = blockIdx.x * blockDim.x + threadIdx.x; i < n16;
       i += gridDim.x * blockDim.x)
    p[i] = make_uint4(0u, 0u, 0u, 0u);
}

struct LayerDesc {
  const u16* A0; int lda0;
  const u16* A1; int lda1; int klen0;
  const void* W0; int ldw0;
  const void* W1; int ldw1; int Ktot;
  const float* bias;   // fp32 [4096] original gate-blocked
  const float* wcol;   // fp32 [4096] dec input column, or null
  const float* inp;    // fp32 [B] scalar input, or null
  float* c;
  u16* h;
  int active;
};

// Paired LSTM step: blockIdx.y<4 -> dA (layer0 @ t), >=4 -> dB (layer1 @ t-1).
// Each 64x64 tile: gates = [A0|A1] @ [W0|W1]^T + bias (+inp*wcol), fused cell.
//
// v3 = Round-0 pipeline (reg-staged loads, single LDS buffer, 2 barriers/chunk
//      -- the proven global-memory path) + FRAGMENT-MAJOR LDS layout:
//   AsF/BsF[unit][lane][8 bf16]; unit u holds M/N rows (u>=4 ? 32:0)+((u&3)>>1)*16
//   + l16 at k-sub (u&1)*32 + quad*8.  Each thread loads exactly its fragment
//   16B from global, so every ds_write_b128 / ds_read_b128 is base + lane*16:
//   ZERO bank conflicts (old [64][72] layout was 8-way on both sides).
template <bool WF32>
__global__ __launch_bounds__(256) void lstm_step_kernel(LayerDesc dA, LayerDesc dB)
{
  const bool second = (blockIdx.y >= 4);
  const LayerDesc d = second ? dB : dA;
  if (!d.active) return;

  __shared__ __align__(16) u16 AsF[8][64][8];  // 8 KB
  __shared__ __align__(16) u16 BsF[8][64][8];  // 8 KB
  __shared__ float Gs[64][68];                 // 17.4 KB

  const int tid = threadIdx.x;
  const int m0 = (second ? (blockIdx.y - 4) : blockIdx.y) * 64;
  const int n0 = blockIdx.x * 64;
  const int ub = n0 >> 2;        // first hidden unit of this block
  const int lane = tid & 63;
  const int wv = tid >> 6;
  const int wm = (wv >> 1) * 32;
  const int wn = (wv & 1) * 32;
  const int l16 = lane & 15;
  const int quad = lane >> 4;    // 0..3
  const int klen0 = d.klen0;

  // Staging: wave wv fills units {wv, wv+4} of both AsF and BsF.
  // Thread's fragment element: k-sub kloc, A-row am1 (unit wv) / am1+32 (wv+4),
  // B gate-col gc (unit wv) / gc+32 (wv+4).
  const int kloc = (wv & 1) * 32 + quad * 8;
  const int am1 = (wv >> 1) * 16 + l16;
  const u16* a0r1 = d.A0 + (size_t)(m0 + am1) * d.lda0;
  const u16* a0r2 = d.A0 + (size_t)(m0 + am1 + 32) * d.lda0;
  const u16* a1r1 = d.A1 + (size_t)(m0 + am1) * d.lda1;
  const u16* a1r2 = d.A1 + (size_t)(m0 + am1 + 32) * d.lda1;

  const int gc = (wv >> 1) * 16 + l16;              // local gate-col, unit wv
  const int orow = (gc & 3) * H_ + ub + (gc >> 2);  // -> original W row; +32 cols = +8 rows
  const u16* b0r1 = (const u16*)d.W0 + (size_t)orow * d.ldw0;
  const u16* b0r2 = b0r1 + (size_t)8 * d.ldw0;
  const u16* b1r1 = (const u16*)d.W1 + (size_t)orow * d.ldw1;
  const u16* b1r2 = b1r1 + (size_t)8 * d.ldw1;
  const float* f0r1 = (const float*)d.W0 + (size_t)orow * d.ldw0;
  const float* f0r2 = f0r1 + (size_t)8 * d.ldw0;
  const float* f1r1 = (const float*)d.W1 + (size_t)orow * d.ldw1;
  const float* f1r2 = f1r1 + (size_t)8 * d.ldw1;

  uint4 avA, avB, bvA, bvB;
  float4 fB[4];

  auto load_chunk = [&](int kc) {
    const int k = kc * 64 + kloc;
    const bool first = k < klen0;   // klen0 % 64 == 0 -> uniform per chunk
    const int kk = first ? k : k - klen0;
    avA = *(const uint4*)((first ? a0r1 : a1r1) + kk);
    avB = *(const uint4*)((first ? a0r2 : a1r2) + kk);
    if constexpr (WF32) {
      const float* p1 = (first ? f0r1 : f1r1) + kk;
      const float* p2 = (first ? f0r2 : f1r2) + kk;
      fB[0] = *(const float4*)p1;
      fB[1] = *(const float4*)(p1 + 4);
      fB[2] = *(const float4*)p2;
      fB[3] = *(const float4*)(p2 + 4);
    } else {
      bvA = *(const uint4*)((first ? b0r1 : b1r1) + kk);
      bvB = *(const uint4*)((first ? b0r2 : b1r2) + kk);
    }
  };

  float4v acc00 = {}, acc01 = {}, acc10 = {}, acc11 = {};
  const int nch = d.Ktot >> 6;
  load_chunk(0);
  for (int kc = 0; kc < nch; ++kc) {
    if constexpr (WF32) {
      bvA = make_uint4(pack2(fB[0].x, fB[0].y), pack2(fB[0].z, fB[0].w),
                       pack2(fB[1].x, fB[1].y), pack2(fB[1].z, fB[1].w));
      bvB = make_uint4(pack2(fB[2].x, fB[2].y), pack2(fB[2].z, fB[2].w),
                       pack2(fB[3].x, fB[3].y), pack2(fB[3].z, fB[3].w));
    }
    __syncthreads();  // previous chunk's LDS readers done
    *(uint4*)&AsF[wv][lane][0]     = avA;   // base + lane*16: conflict-free
    *(uint4*)&AsF[wv + 4][lane][0] = avB;
    *(uint4*)&BsF[wv][lane][0]     = bvA;
    *(uint4*)&BsF[wv + 4][lane][0] = bvB;
    __syncthreads();
    if (kc + 1 < nch) load_chunk(kc + 1);  // in flight across MFMA below
#pragma unroll
    for (int ks = 0; ks < 2; ++ks) {
      // unit index: (wm|wn)>>3 gives 0 or 4; +ks / +2+ks selects k-sub & 16-row half
      const short8 a0 = *(const short8*)&AsF[(wm >> 3) + ks][lane][0];
      const short8 a1 = *(const short8*)&AsF[(wm >> 3) + 2 + ks][lane][0];
      const short8 b0 = *(const short8*)&BsF[(wn >> 3) + ks][lane][0];
      const short8 b1 = *(const short8*)&BsF[(wn >> 3) + 2 + ks][lane][0];
      acc00 = __builtin_amdgcn_mfma_f32_16x16x32_bf16(a0, b0, acc00, 0, 0, 0);
      acc01 = __builtin_amdgcn_mfma_f32_16x16x32_bf16(a0, b1, acc01, 0, 0, 0);
      acc10 = __builtin_amdgcn_mfma_f32_16x16x32_bf16(a1, b0, acc10, 0, 0, 0);
      acc11 = __builtin_amdgcn_mfma_f32_16x16x32_bf16(a1, b1, acc11, 0, 0, 0);
    }
  }

  // spill gates to LDS (C/D layout: col = lane&15, row = quad*4 + reg)
#pragma unroll
  for (int rr = 0; rr < 4; ++rr) {
    Gs[wm + quad * 4 + rr][wn + l16]           = acc00[rr];
    Gs[wm + quad * 4 + rr][wn + 16 + l16]      = acc01[rr];
    Gs[wm + 16 + quad * 4 + rr][wn + l16]      = acc10[rr];
    Gs[wm + 16 + quad * 4 + rr][wn + 16 + l16] = acc11[rr];
  }
  __syncthreads();

  // fused LSTM cell: 64 batches x 16 units; local col 4u+g = gate g of unit ub+u
#pragma unroll
  for (int it = 0; it < 4; ++it) {
    const int p = tid + it * 256;
    const int bl = p >> 4;
    const int u = p & 15;
    const int J = ub + u;
    const int bg = m0 + bl;
    const float4v g = *(const float4v*)&Gs[bl][u * 4];
    float pi = g[0] + d.bias[J];
    float pf = g[1] + d.bias[H_ + J];
    float pg = g[2] + d.bias[2 * H_ + J];
    float po = g[3] + d.bias[3 * H_ + J];
    if (d.inp != nullptr) {
      const float iv = d.inp[bg];
      pi += iv * d.wcol[J];
      pf += iv * d.wcol[H_ + J];
      pg += iv * d.wcol[2 * H_ + J];
      po += iv * d.wcol[3 * H_ + J];
    }
    const size_t idx = (size_t)bg * H_ + J;
    const float c = d.c[idx];
    const float cn = sigm(pf) * c + sigm(pi) * tanh_(pg);
    d.c[idx] = cn;
    d.h[idx] = f2bf(sigm(po) * tanh_(cn));
  }
}

// pred[b] = fc_W . h1[b] + fc_b ; fp32 out + fp32 feedback
__global__ __launch_bounds__(256) void fc_kernel(
    const u16* __restrict__ h1, const float* __restrict__ fcW,
    const float* __restrict__ fcb, float* __restrict__ out,
    float* __restrict__ inp, int t)
{
  const int b = blockIdx.x;
  const int tid = threadIdx.x;
  const u16* hr = h1 + (size_t)b * H_ + tid * 4;
  const float* wr = fcW + tid * 4;
  float s = 0.f;
#pragma unroll
  for (int j = 0; j < 4; ++j) s += bf2f(hr[j]) * wr[j];
#pragma unroll
  for (int off = 32; off > 0; off >>= 1) s += __shfl_down(s, off, 64);
  __shared__ float red[4];
  if ((tid & 63) == 0) red[tid >> 6] = s;
  __syncthreads();
  if (tid == 0) {
    const float p = red[0] + red[1] + red[2] + red[3] + fcb[0];
    out[(size_t)b * TOUT + t] = p;
    inp[b] = p;
  }
}

extern "C" void kernel_launch(void* const* d_in, const int* in_sizes, int n_in,
                              void* d_out, int out_size, void* d_ws, size_t ws_size,
                              hipStream_t stream)
{
  const float* X     = (const float*)d_in[0];
  const float* eWih0 = (const float*)d_in[1];
  const float* eWhh0 = (const float*)d_in[2];
  const float* eb0   = (const float*)d_in[3];
  const float* eWih1 = (const float*)d_in[4];
  const float* eWhh1 = (const float*)d_in[5];
  const float* eb1   = (const float*)d_in[6];
  const float* dWih0 = (const float*)d_in[7];
  const float* dWhh0 = (const float*)d_in[8];
  const float* db0   = (const float*)d_in[9];
  const float* dWih1 = (const float*)d_in[10];
  const float* dWhh1 = (const float*)d_in[11];
  const float* db1   = (const float*)d_in[12];
  const float* fcW   = (const float*)d_in[13];
  const float* fcb   = (const float*)d_in[14];
  float* out = (float*)d_out;

  char* ws = (char*)d_ws;
  size_t off = 0;
  auto alloc = [&](size_t bytes) -> void* {
    void* p = ws + off;
    off += (bytes + 255) & ~(size_t)255;
    return p;
  };
  // state block first (zeroed every call)
  u16* h0buf[2], *h1buf[2];
  h0buf[0] = (u16*)alloc((size_t)B_ * H_ * 2);
  h0buf[1] = (u16*)alloc((size_t)B_ * H_ * 2);
  h1buf[0] = (u16*)alloc((size_t)B_ * H_ * 2);
  h1buf[1] = (u16*)alloc((size_t)B_ * H_ * 2);
  float* C0  = (float*)alloc((size_t)B_ * H_ * 4);
  float* C1  = (float*)alloc((size_t)B_ * H_ * 4);
  float* INP = (float*)alloc(B_ * 4);
  const size_t zbytes = off;
  u16* XB = (u16*)alloc((size_t)B_ * S_ * D_ * 2);
  // bf16 weight copies (fast path), original flat layouts
  u16* WB_eWih0 = (u16*)alloc((size_t)G4 * D_ * 2);
  u16* WB_eWhh0 = (u16*)alloc((size_t)G4 * H_ * 2);
  u16* WB_eWih1 = (u16*)alloc((size_t)G4 * H_ * 2);
  u16* WB_eWhh1 = (u16*)alloc((size_t)G4 * H_ * 2);
  u16* WB_dWhh0 = (u16*)alloc((size_t)G4 * H_ * 2);
  u16* WB_dWih1 = (u16*)alloc((size_t)G4 * H_ * 2);
  u16* WB_dWhh1 = (u16*)alloc((size_t)G4 * H_ * 2);
  const size_t need_full = off;
  const bool fast = (ws_size >= need_full);

  zero_kernel<<<dim3(256), dim3(256), 0, stream>>>((uint4*)ws, (int)(zbytes / 16));
  cvt_kernel<<<dim3(1024), dim3(256), 0, stream>>>(X, XB, B_ * S_ * D_);
  if (fast) {
    cvt_kernel<<<dim3(256), dim3(256), 0, stream>>>(eWih0, WB_eWih0, G4 * D_);
    cvt_kernel<<<dim3(1024), dim3(256), 0, stream>>>(eWhh0, WB_eWhh0, G4 * H_);
    cvt_kernel<<<dim3(1024), dim3(256), 0, stream>>>(eWih1, WB_eWih1, G4 * H_);
    cvt_kernel<<<dim3(1024), dim3(256), 0, stream>>>(eWhh1, WB_eWhh1, G4 * H_);
    cvt_kernel<<<dim3(1024), dim3(256), 0, stream>>>(dWhh0, WB_dWhh0, G4 * H_);
    cvt_kernel<<<dim3(1024), dim3(256), 0, stream>>>(dWih1, WB_dWih1, G4 * H_);
    cvt_kernel<<<dim3(1024), dim3(256), 0, stream>>>(dWhh1, WB_dWhh1, G4 * H_);
  }

  auto mk = [&](const u16* A0, int lda0, const u16* A1, int lda1, int klen0,
                const void* W0b, const void* W0f, int ldw0,
                const void* W1b, const void* W1f, int ldw1, int Ktot,
                const float* bias, const float* wcol, const float* inp,
                float* c, u16* h) {
    LayerDesc d;
    d.A0 = A0; d.lda0 = lda0; d.A1 = A1; d.lda1 = lda1; d.klen0 = klen0;
    d.W0 = fast ? W0b : W0f; d.ldw0 = ldw0;
    d.W1 = fast ? W1b : W1f; d.ldw1 = ldw1; d.Ktot = Ktot;
    d.bias = bias; d.wcol = wcol; d.inp = inp; d.c = c; d.h = h;
    d.active = 1;
    return d;
  };
  LayerDesc off_d = {};
  off_d.active = 0;

  auto launch = [&](dim3 grid, const LayerDesc& a, const LayerDesc& b) {
    if (fast)
      lstm_step_kernel<false><<<grid, dim3(256), 0, stream>>>(a, b);
    else
      lstm_step_kernel<true><<<grid, dim3(256), 0, stream>>>(a, b);
  };

  // encoder, layer-pipelined: tick u runs L0(t=u) and L1(t=u-1) concurrently.
  // h ping-pong: L(t) reads hbuf[t&1], writes hbuf[(t+1)&1].
  for (int u = 0; u <= S_; ++u) {
    LayerDesc d0 = off_d, d1 = off_d;
    if (u < S_) {
      const int t = u;
      d0 = mk(XB + t * D_, S_ * D_, h0buf[t & 1], H_, D_,
              WB_eWih0, eWih0, D_, WB_eWhh0, eWhh0, H_, 1088,
              eb0, nullptr, nullptr, C0, h0buf[(t + 1) & 1]);
    }
    if (u >= 1) {
      const int t = u - 1;
      d1 = mk(h0buf[(t + 1) & 1], H_, h1buf[t & 1], H_, H_,
              WB_eWih1, eWih1, H_, WB_eWhh1, eWhh1, H_, 2048,
              eb1, nullptr, nullptr, C1, h1buf[(t + 1) & 1]);
    }
    launch(dim3(64, 8), d0, d1);
  }

  // decoder: strictly sequential (pred feedback), single-layer launches
  for (int t = 0; t < TOUT; ++t) {
    u16* h0i = h0buf[t & 1]; u16* h0o = h0buf[(t + 1) & 1];
    u16* h1i = h1buf[t & 1]; u16* h1o = h1buf[(t + 1) & 1];
    LayerDesc dl0 = mk(h0i, H_, h0i, H_, 1024,
                       WB_dWhh0, dWhh0, H_, WB_dWhh0, dWhh0, H_, 1024,
                       db0, dWih0, INP, C0, h0o);
    launch(dim3(64, 4), dl0, off_d);
    LayerDesc dl1 = mk(h0o, H_, h1i, H_, H_,
                       WB_dWih1, dWih1, H_, WB_dWhh1, dWhh1, H_, 2048,
                       db1, nullptr, nullptr, C1, h1o);
    launch(dim3(64, 4), dl1, off_d);
    fc_kernel<<<dim3(B_), dim3(256), 0, stream>>>(h1o, fcW, fcb, out, INP, t);
  }
}

// Round 3
// 6183.131 us; speedup vs baseline: 2.2481x; 1.6906x over previous
//
#include <hip/hip_runtime.h>

#define B_ 256
#define S_ 256
#define D_ 64
#define H_ 1024
#define G4 4096
#define TOUT 32

typedef unsigned short u16;
typedef __attribute__((ext_vector_type(8))) short short8;
typedef __attribute__((ext_vector_type(4))) float float4v;

__device__ __forceinline__ float bf2f(u16 b) {
  return __uint_as_float(((unsigned int)b) << 16);
}
__device__ __forceinline__ u16 f2bf(float f) {
  unsigned int u = __float_as_uint(f);
  unsigned int r = (u + 0x7fffu + ((u >> 16) & 1u)) >> 16;
  return (u16)r;
}
__device__ __forceinline__ unsigned pack2(float a, float b) {
  return (unsigned)f2bf(a) | ((unsigned)f2bf(b) << 16);
}
__device__ __forceinline__ float sigm(float x) {
  return 1.f / (1.f + __expf(-x));
}
__device__ __forceinline__ float tanh_(float x) {
  float xc = fminf(fmaxf(x, -15.f), 15.f);
  float e = __expf(2.f * xc);
  return (e - 1.f) / (e + 1.f);
}

__global__ __launch_bounds__(256) void cvt_kernel(const float* __restrict__ src,
                                                  u16* __restrict__ dst, int n) {
  for (int i = blockIdx.x * blockDim.x + threadIdx.x; i < n;
       i += gridDim.x * blockDim.x)
    dst[i] = f2bf(src[i]);
}

__global__ __launch_bounds__(256) void zero_kernel(uint4* __restrict__ p, int n16) {
  for (int i = blockIdx.x * blockDim.x + threadIdx.x; i < n16;
       i += gridDim.x * blockDim.x)
    p[i] = make_uint4(0u, 0u, 0u, 0u);
}

struct LayerDesc {
  const u16* A0; int lda0;
  const u16* A1; int lda1; int klen0;
  const void* W0; int ldw0;
  const void* W1; int ldw1; int Ktot;
  const float* bias;   // fp32 [4096] original gate-blocked
  const float* wcol;   // fp32 [4096] dec input column, or null
  const float* inp;    // fp32 [B] scalar input, or null
  float* c;
  u16* h;
  int active;
};

// Paired LSTM step: blockIdx.y<4 -> dA (layer0 @ t), >=4 -> dB (layer1 @ t-1).
// Each 64x64 tile: gates = [A0|A1] @ [W0|W1]^T + bias (+inp*wcol), fused cell.
//
// v4 = v1's exact memory path (reg-staged loads, padded [64][72] LDS — measured
// near-conflict-free by the balanced-bank model) + LDS DOUBLE-BUFFER with ONE
// __syncthreads per K-chunk (v1 had two).  Iter kc: MFMA on buf[kc&1] ->
// vmcnt-gated ds_write of chunk kc+1 into the other buf -> issue loads kc+2 ->
// barrier.  The end-of-iter barrier separates this iter's writes from last
// iter's reads of the same buffer, so one barrier per chunk is sufficient.
template <bool WF32>
__global__ __launch_bounds__(256) void lstm_step_kernel(LayerDesc dA, LayerDesc dB)
{
  const bool second = (blockIdx.y >= 4);
  const LayerDesc d = second ? dB : dA;
  if (!d.active) return;

  __shared__ u16 As[2][64][72];   // +8 pad (v1 layout), 18 KB each
  __shared__ u16 Bs[2][64][72];
  __shared__ float Gs[64][68];

  const int tid = threadIdx.x;
  const int m0 = (second ? (blockIdx.y - 4) : blockIdx.y) * 64;
  const int n0 = blockIdx.x * 64;
  const int ub = n0 >> 2;        // first hidden unit of this block
  const int r = tid >> 2;        // staging row 0..63
  const int q = tid & 3;         // staging 16-col group
  const int lane = tid & 63;
  const int wv = tid >> 6;
  const int wm = (wv >> 1) * 32;
  const int wn = (wv & 1) * 32;
  const int l16 = lane & 15;
  const int quad = lane >> 4;

  const int klen0 = d.klen0;
  const u16* aw0 = d.A0 + (size_t)(m0 + r) * d.lda0;
  const u16* aw1 = d.A1 + (size_t)(m0 + r) * d.lda1;
  const int orow = (r & 3) * H_ + ub + (r >> 2);  // gate-col n0+r -> original W row
  const u16* bw0_h = (const u16*)d.W0 + (size_t)orow * d.ldw0;
  const u16* bw1_h = (const u16*)d.W1 + (size_t)orow * d.ldw1;
  const float* bw0_f = (const float*)d.W0 + (size_t)orow * d.ldw0;
  const float* bw1_f = (const float*)d.W1 + (size_t)orow * d.ldw1;

  uint4 av0, av1, bv0, bv1;
  float4 bf0, bf1, bf2, bf3;

  auto load_chunk = [&](int kc) {
    const int kg = kc * 64 + q * 16;
    const bool first = kg < klen0;
    const u16* pa = first ? (aw0 + kg) : (aw1 + (kg - klen0));
    av0 = *(const uint4*)pa;
    av1 = *(const uint4*)(pa + 8);
    if constexpr (WF32) {
      const float* pb = first ? (bw0_f + kg) : (bw1_f + (kg - klen0));
      bf0 = *(const float4*)pb;
      bf1 = *(const float4*)(pb + 4);
      bf2 = *(const float4*)(pb + 8);
      bf3 = *(const float4*)(pb + 12);
    } else {
      const u16* pb = first ? (bw0_h + kg) : (bw1_h + (kg - klen0));
      bv0 = *(const uint4*)pb;
      bv1 = *(const uint4*)(pb + 8);
    }
  };

  auto stage = [&](int buf) {  // regs -> LDS (vmcnt auto-gated by compiler)
    if constexpr (WF32) {
      bv0 = make_uint4(pack2(bf0.x, bf0.y), pack2(bf0.z, bf0.w),
                       pack2(bf1.x, bf1.y), pack2(bf1.z, bf1.w));
      bv1 = make_uint4(pack2(bf2.x, bf2.y), pack2(bf2.z, bf2.w),
                       pack2(bf3.x, bf3.y), pack2(bf3.z, bf3.w));
    }
    *(uint4*)&As[buf][r][q * 16]     = av0;
    *(uint4*)&As[buf][r][q * 16 + 8] = av1;
    *(uint4*)&Bs[buf][r][q * 16]     = bv0;
    *(uint4*)&Bs[buf][r][q * 16 + 8] = bv1;
  };

  float4v acc00 = {}, acc01 = {}, acc10 = {}, acc11 = {};
  const int nch = d.Ktot >> 6;

  load_chunk(0);
  stage(0);
  if (nch > 1) load_chunk(1);
  __syncthreads();  // buf0 ready

  for (int kc = 0; kc < nch; ++kc) {
    const int cur = kc & 1;
#pragma unroll
    for (int ks = 0; ks < 2; ++ks) {
      const int kb = ks * 32 + quad * 8;
      short8 a0 = *(const short8*)&As[cur][wm + l16][kb];
      short8 a1 = *(const short8*)&As[cur][wm + 16 + l16][kb];
      short8 b0 = *(const short8*)&Bs[cur][wn + l16][kb];
      short8 b1 = *(const short8*)&Bs[cur][wn + 16 + l16][kb];
      acc00 = __builtin_amdgcn_mfma_f32_16x16x32_bf16(a0, b0, acc00, 0, 0, 0);
      acc01 = __builtin_amdgcn_mfma_f32_16x16x32_bf16(a0, b1, acc01, 0, 0, 0);
      acc10 = __builtin_amdgcn_mfma_f32_16x16x32_bf16(a1, b0, acc10, 0, 0, 0);
      acc11 = __builtin_amdgcn_mfma_f32_16x16x32_bf16(a1, b1, acc11, 0, 0, 0);
    }
    if (kc + 1 < nch) {
      stage(cur ^ 1);                         // chunk kc+1 (regs held since last iter)
      if (kc + 2 < nch) load_chunk(kc + 2);   // ~1.5 chunks to complete
      __syncthreads();                        // buf cur^1 ready; next iter's writes fenced
    }
  }

  // spill gates to LDS (C/D layout: col = lane&15, row = quad*4 + reg)
#pragma unroll
  for (int rr = 0; rr < 4; ++rr) {
    Gs[wm + quad * 4 + rr][wn + l16]           = acc00[rr];
    Gs[wm + quad * 4 + rr][wn + 16 + l16]      = acc01[rr];
    Gs[wm + 16 + quad * 4 + rr][wn + l16]      = acc10[rr];
    Gs[wm + 16 + quad * 4 + rr][wn + 16 + l16] = acc11[rr];
  }
  __syncthreads();

  // fused LSTM cell: 64 batches x 16 units; local col 4u+g = gate g of unit ub+u
#pragma unroll
  for (int it = 0; it < 4; ++it) {
    const int p = tid + it * 256;
    const int bl = p >> 4;
    const int u = p & 15;
    const int J = ub + u;
    const int bg = m0 + bl;
    const float4v g = *(const float4v*)&Gs[bl][u * 4];
    float pi = g[0] + d.bias[J];
    float pf = g[1] + d.bias[H_ + J];
    float pg = g[2] + d.bias[2 * H_ + J];
    float po = g[3] + d.bias[3 * H_ + J];
    if (d.inp != nullptr) {
      const float iv = d.inp[bg];
      pi += iv * d.wcol[J];
      pf += iv * d.wcol[H_ + J];
      pg += iv * d.wcol[2 * H_ + J];
      po += iv * d.wcol[3 * H_ + J];
    }
    const size_t idx = (size_t)bg * H_ + J;
    const float c = d.c[idx];
    const float cn = sigm(pf) * c + sigm(pi) * tanh_(pg);
    d.c[idx] = cn;
    d.h[idx] = f2bf(sigm(po) * tanh_(cn));
  }
}

// pred[b] = fc_W . h1[b] + fc_b ; fp32 out + fp32 feedback
__global__ __launch_bounds__(256) void fc_kernel(
    const u16* __restrict__ h1, const float* __restrict__ fcW,
    const float* __restrict__ fcb, float* __restrict__ out,
    float* __restrict__ inp, int t)
{
  const int b = blockIdx.x;
  const int tid = threadIdx.x;
  const u16* hr = h1 + (size_t)b * H_ + tid * 4;
  const float* wr = fcW + tid * 4;
  float s = 0.f;
#pragma unroll
  for (int j = 0; j < 4; ++j) s += bf2f(hr[j]) * wr[j];
#pragma unroll
  for (int off = 32; off > 0; off >>= 1) s += __shfl_down(s, off, 64);
  __shared__ float red[4];
  if ((tid & 63) == 0) red[tid >> 6] = s;
  __syncthreads();
  if (tid == 0) {
    const float p = red[0] + red[1] + red[2] + red[3] + fcb[0];
    out[(size_t)b * TOUT + t] = p;
    inp[b] = p;
  }
}

extern "C" void kernel_launch(void* const* d_in, const int* in_sizes, int n_in,
                              void* d_out, int out_size, void* d_ws, size_t ws_size,
                              hipStream_t stream)
{
  const float* X     = (const float*)d_in[0];
  const float* eWih0 = (const float*)d_in[1];
  const float* eWhh0 = (const float*)d_in[2];
  const float* eb0   = (const float*)d_in[3];
  const float* eWih1 = (const float*)d_in[4];
  const float* eWhh1 = (const float*)d_in[5];
  const float* eb1   = (const float*)d_in[6];
  const float* dWih0 = (const float*)d_in[7];
  const float* dWhh0 = (const float*)d_in[8];
  const float* db0   = (const float*)d_in[9];
  const float* dWih1 = (const float*)d_in[10];
  const float* dWhh1 = (const float*)d_in[11];
  const float* db1   = (const float*)d_in[12];
  const float* fcW   = (const float*)d_in[13];
  const float* fcb   = (const float*)d_in[14];
  float* out = (float*)d_out;

  char* ws = (char*)d_ws;
  size_t off = 0;
  auto alloc = [&](size_t bytes) -> void* {
    void* p = ws + off;
    off += (bytes + 255) & ~(size_t)255;
    return p;
  };
  // state block first (zeroed every call)
  u16* h0buf[2], *h1buf[2];
  h0buf[0] = (u16*)alloc((size_t)B_ * H_ * 2);
  h0buf[1] = (u16*)alloc((size_t)B_ * H_ * 2);
  h1buf[0] = (u16*)alloc((size_t)B_ * H_ * 2);
  h1buf[1] = (u16*)alloc((size_t)B_ * H_ * 2);
  float* C0  = (float*)alloc((size_t)B_ * H_ * 4);
  float* C1  = (float*)alloc((size_t)B_ * H_ * 4);
  float* INP = (float*)alloc(B_ * 4);
  const size_t zbytes = off;
  u16* XB = (u16*)alloc((size_t)B_ * S_ * D_ * 2);
  // bf16 weight copies (fast path), original flat layouts
  u16* WB_eWih0 = (u16*)alloc((size_t)G4 * D_ * 2);
  u16* WB_eWhh0 = (u16*)alloc((size_t)G4 * H_ * 2);
  u16* WB_eWih1 = (u16*)alloc((size_t)G4 * H_ * 2);
  u16* WB_eWhh1 = (u16*)alloc((size_t)G4 * H_ * 2);
  u16* WB_dWhh0 = (u16*)alloc((size_t)G4 * H_ * 2);
  u16* WB_dWih1 = (u16*)alloc((size_t)G4 * H_ * 2);
  u16* WB_dWhh1 = (u16*)alloc((size_t)G4 * H_ * 2);
  const size_t need_full = off;
  const bool fast = (ws_size >= need_full);

  zero_kernel<<<dim3(256), dim3(256), 0, stream>>>((uint4*)ws, (int)(zbytes / 16));
  cvt_kernel<<<dim3(1024), dim3(256), 0, stream>>>(X, XB, B_ * S_ * D_);
  if (fast) {
    cvt_kernel<<<dim3(256), dim3(256), 0, stream>>>(eWih0, WB_eWih0, G4 * D_);
    cvt_kernel<<<dim3(1024), dim3(256), 0, stream>>>(eWhh0, WB_eWhh0, G4 * H_);
    cvt_kernel<<<dim3(1024), dim3(256), 0, stream>>>(eWih1, WB_eWih1, G4 * H_);
    cvt_kernel<<<dim3(1024), dim3(256), 0, stream>>>(eWhh1, WB_eWhh1, G4 * H_);
    cvt_kernel<<<dim3(1024), dim3(256), 0, stream>>>(dWhh0, WB_dWhh0, G4 * H_);
    cvt_kernel<<<dim3(1024), dim3(256), 0, stream>>>(dWih1, WB_dWih1, G4 * H_);
    cvt_kernel<<<dim3(1024), dim3(256), 0, stream>>>(dWhh1, WB_dWhh1, G4 * H_);
  }

  auto mk = [&](const u16* A0, int lda0, const u16* A1, int lda1, int klen0,
                const void* W0b, const void* W0f, int ldw0,
                const void* W1b, const void* W1f, int ldw1, int Ktot,
                const float* bias, const float* wcol, const float* inp,
                float* c, u16* h) {
    LayerDesc d;
    d.A0 = A0; d.lda0 = lda0; d.A1 = A1; d.lda1 = lda1; d.klen0 = klen0;
    d.W0 = fast ? W0b : W0f; d.ldw0 = ldw0;
    d.W1 = fast ? W1b : W1f; d.ldw1 = ldw1; d.Ktot = Ktot;
    d.bias = bias; d.wcol = wcol; d.inp = inp; d.c = c; d.h = h;
    d.active = 1;
    return d;
  };
  LayerDesc off_d = {};
  off_d.active = 0;

  auto launch = [&](dim3 grid, const LayerDesc& a, const LayerDesc& b) {
    if (fast)
      lstm_step_kernel<false><<<grid, dim3(256), 0, stream>>>(a, b);
    else
      lstm_step_kernel<true><<<grid, dim3(256), 0, stream>>>(a, b);
  };

  // encoder, layer-pipelined: tick u runs L0(t=u) and L1(t=u-1) concurrently.
  // h ping-pong: L(t) reads hbuf[t&1], writes hbuf[(t+1)&1].
  for (int u = 0; u <= S_; ++u) {
    LayerDesc d0 = off_d, d1 = off_d;
    if (u < S_) {
      const int t = u;
      d0 = mk(XB + t * D_, S_ * D_, h0buf[t & 1], H_, D_,
              WB_eWih0, eWih0, D_, WB_eWhh0, eWhh0, H_, 1088,
              eb0, nullptr, nullptr, C0, h0buf[(t + 1) & 1]);
    }
    if (u >= 1) {
      const int t = u - 1;
      d1 = mk(h0buf[(t + 1) & 1], H_, h1buf[t & 1], H_, H_,
              WB_eWih1, eWih1, H_, WB_eWhh1, eWhh1, H_, 2048,
              eb1, nullptr, nullptr, C1, h1buf[(t + 1) & 1]);
    }
    launch(dim3(64, 8), d0, d1);
  }

  // decoder: strictly sequential (pred feedback), single-layer launches
  for (int t = 0; t < TOUT; ++t) {
    u16* h0i = h0buf[t & 1]; u16* h0o = h0buf[(t + 1) & 1];
    u16* h1i = h1buf[t & 1]; u16* h1o = h1buf[(t + 1) & 1];
    LayerDesc dl0 = mk(h0i, H_, h0i, H_, 1024,
                       WB_dWhh0, dWhh0, H_, WB_dWhh0, dWhh0, H_, 1024,
                       db0, dWih0, INP, C0, h0o);
    launch(dim3(64, 4), dl0, off_d);
    LayerDesc dl1 = mk(h0o, H_, h1i, H_, H_,
                       WB_dWih1, dWih1, H_, WB_dWhh1, dWhh1, H_, 2048,
                       db1, nullptr, nullptr, C1, h1o);
    launch(dim3(64, 4), dl1, off_d);
    fc_kernel<<<dim3(B_), dim3(256), 0, stream>>>(h1o, fcW, fcb, out, INP, t);
  }
}